// Round 1
// 365.483 us; speedup vs baseline: 1.1552x; 1.1552x over previous
//
#include <hip/hip_runtime.h>

#define NA 51          // atoms
#define ROWS 256       // rows per block == threads per block

// C51 Bellman projection, thread-per-row, flat (unpadded) LDS coalescing buffer.
// Row-uniform shift s = reward*2.5, k=floor(s), f=frac(s):
//   out[i] = (1-f)*p[i-k]*[valid] + f*p[i-k-1]*[valid] + (i==0)*m_lo + (i==50)*m_hi
// m_lo = sum p[j] over j+s<0 (clamped low), m_hi = sum p[j] over j+s>50.
//
// Key change vs previous version: output row is accumulated into a fully
// unrolled register array o[51] (static indices only), so ALL LDS reads for a
// row are independent and issue before any LDS write. This removes the 51-deep
// read-modify-write LDS latency chain that made the old kernel latency-bound.
// Flat identity LDS layout makes staging/copy-out conflict-free b128 copies,
// and row stride 51 (odd) makes per-row scalar LDS access conflict-free.
__global__ __launch_bounds__(256, 3) void c51_bellman_kernel(
    const float* __restrict__ reward,
    const float* __restrict__ probs,
    float* __restrict__ out,
    int bs)
{
    __shared__ float lds[ROWS * NA];   // 52224 B -> 3 blocks/CU (LDS-limited)
    const int tid   = threadIdx.x;
    const int row0  = blockIdx.x * ROWS;
    const int nrows = min(ROWS, bs - row0);
    const int nelem = nrows * NA;
    const int n4    = nelem >> 2;

    // ---- stage: coalesced float4 global loads -> identity float4 LDS writes ----
    // base byte offset = row0*51*4 = blockIdx*52224, 52224 % 16 == 0 -> aligned
    const float4* p4 = (const float4*)(probs + (size_t)row0 * NA);
    float4* l4 = (float4*)lds;
    for (int e4 = tid; e4 < n4; e4 += ROWS) l4[e4] = p4[e4];
    // scalar tail (not hit for bs=1e6 shapes, kept for correctness)
    for (int e = (n4 << 2) + tid; e < nelem; e += ROWS)
        lds[e] = probs[(size_t)row0 * NA + e];
    __syncthreads();

    // ---- per-thread row compute, output accumulated in registers ----
    if (tid < nrows) {
        const float s  = reward[row0 + tid] * 2.5f;  // r / 0.4
        const float kf = floorf(s);
        const int   k  = (int)kf;
        const float f  = s - kf;
        const float* rp = lds + tid * NA;            // own row, stride 51 dwords

        // pass A: clamp masses (51 independent static-offset LDS reads)
        float m_lo = 0.0f, m_hi = 0.0f;
        #pragma unroll
        for (int j = 0; j < NA; ++j) {
            const float pj = rp[j];
            const float t  = (float)j + s;
            if (t < 0.0f)  m_lo += pj;
            if (t > 50.0f) m_hi += pj;
        }

        // pass B: sliding-window gather. 52 independent dynamic LDS reads;
        // value at source j = i-k is reused as "prev" for i+1 (upper term).
        float o[NA];
        float prev;
        {
            const int jm = -k - 1;                   // source of upper term at i=0
            const int cm = min(max(jm, 0), NA - 1);
            const float v = rp[cm];
            prev = (jm >= 0 && jm < NA) ? v : 0.0f;
        }
        #pragma unroll
        for (int i = 0; i < NA; ++i) {
            const int j = i - k;                     // lower-source atom
            const int c = min(max(j, 0), NA - 1);
            const float v = rp[c];
            const float cur = (j >= 0 && j < NA) ? v : 0.0f;
            // (1-f)*p[i-k] valid while i+f <= 50; f*p[i-k-1] valid while i-1+f >= 0
            const float w1 = ((float)i + f <= 50.0f) ? (1.0f - f) : 0.0f;
            const float w2 = ((float)(i - 1) + f >= 0.0f) ? f : 0.0f;
            o[i] = w1 * cur + w2 * prev;
            prev = cur;
        }
        o[0]      += m_lo;
        o[NA - 1] += m_hi;

        // write back in-place (own row only; all reads above already issued)
        float* wp = lds + tid * NA;
        #pragma unroll
        for (int i = 0; i < NA; ++i) wp[i] = o[i];
    }
    __syncthreads();

    // ---- copy-out: identity LDS b128 reads -> coalesced float4 global stores ----
    float4* o4 = (float4*)(out + (size_t)row0 * NA);
    const float4* l4c = (const float4*)lds;
    for (int e4 = tid; e4 < n4; e4 += ROWS) o4[e4] = l4c[e4];
    for (int e = (n4 << 2) + tid; e < nelem; e += ROWS)
        out[(size_t)row0 * NA + e] = lds[e];
}

extern "C" void kernel_launch(void* const* d_in, const int* in_sizes, int n_in,
                              void* d_out, int out_size, void* d_ws, size_t ws_size,
                              hipStream_t stream) {
    const float* reward = (const float*)d_in[0];
    const float* probs  = (const float*)d_in[1];
    // d_in[2] = atom_values: unused — atom j sits exactly at index j in idx-space
    float* out = (float*)d_out;
    const int bs = in_sizes[0];

    const int blocks = (bs + ROWS - 1) / ROWS;
    c51_bellman_kernel<<<blocks, ROWS, 0, stream>>>(reward, probs, out, bs);
}

// Round 2
// 344.716 us; speedup vs baseline: 1.2248x; 1.0602x over previous
//
#include <hip/hip_runtime.h>

#define NA 51
#define ROWS 64                 // one wave per block
#define GUARD 56                // floats of guard each side (k clamped to +/-52)
#define NDATA (ROWS * NA)       // 3264 floats = 13056 B
#define KCLAMP 52

// C51 Bellman projection, thread-per-row, single-wave blocks.
//   s = reward*2.5, k = floor(s) (clamped to +/-52, provably equivalent), f = frac(s)
//   out[i] = (1-f)*p[i-k]*[0<=i-k<=50] + f*p[i-k-1]*[...] + (i==0)*m_lo + (i==50)*m_hi
// Structure: global_load_lds direct staging (no barriers: intra-wave visibility
// via s_waitcnt only), guarded-window LDS reads with immediate offsets
// (-> ds_read2_b32, no per-read address VALU), fused compute+writeback,
// b128 identity copy-out. 13.5 KB LDS -> 12 independent waves/CU free-running
// at different phases so HBM stays saturated.
__global__ __launch_bounds__(ROWS, 3) void c51_bellman_kernel(
    const float* __restrict__ reward,
    const float* __restrict__ probs,
    float* __restrict__ out,
    int bs)
{
    __shared__ float lds[GUARD + NDATA + GUARD];   // 13504 B
    float* data = lds + GUARD;                     // GUARD*4=224 B, 16B-aligned
    const int tid   = threadIdx.x;
    const int row0  = blockIdx.x * ROWS;
    const int nrows = min(ROWS, bs - row0);

    // reward load issued early; drained by the vmcnt(0) below
    float s = 0.0f;
    if (tid < nrows) s = reward[row0 + tid] * 2.5f;  // r / 0.4

    if (nrows == ROWS) {
        // ---- stage: 12 x 1KB direct global->LDS + 768B tail ----
        // base = blockIdx*13056 bytes -> 16B aligned
        const char* src = (const char*)(probs + (size_t)row0 * NA);
        #pragma unroll
        for (int t = 0; t < 12; ++t) {
            __builtin_amdgcn_global_load_lds(
                (const __attribute__((address_space(1))) void*)
                    (unsigned long long)(src + t * 1024 + tid * 16),
                (__attribute__((address_space(3))) void*)
                    (unsigned long long)(data + t * 256),
                16, 0, 0);
        }
        if (tid < 48) {   // tail: 3264-3072=192 floats = 48 lanes x 16B
            const float4 v = *(const float4*)(src + 12288 + (size_t)tid * 16);
            *(float4*)(data + 3072 + tid * 4) = v;
        }
    } else {
        const int nelem = nrows * NA;
        for (int e = tid; e < nelem; e += ROWS)
            data[e] = probs[(size_t)row0 * NA + e];
    }
    // single-wave block: waitcnt (not barrier) makes LDS writes visible
    asm volatile("s_waitcnt vmcnt(0) lgkmcnt(0)" ::: "memory");
    __builtin_amdgcn_sched_barrier(0);

    if (tid < nrows) {
        const float kf = floorf(s);
        const float f  = s - kf;
        int k = (int)kf;
        k = min(max(k, -KCLAMP), KCLAMP);   // out-of-range k: all terms zero either way

        const float* rp = data + tid * NA;  // own row, lane stride 51 -> conflict-free

        // pass A: clamp masses. Uniform base + immediate offsets -> ds_read2_b32.
        float m_lo = 0.0f, m_hi = 0.0f;
        #pragma unroll
        for (int j = 0; j < NA; ++j) {
            const float pj = rp[j];
            const float t  = (float)j + s;
            if (t < 0.0f)  m_lo += pj;
            if (t > 50.0f) m_hi += pj;
        }

        // pass B window: w[m] = p[m-k-1] (guarded garbage when OOB, masked below).
        // Single per-lane base + immediate offsets -> ds_read2_b32, regs only.
        const float* wb = data + tid * NA - k - 1;
        float w[52];
        #pragma unroll
        for (int m = 0; m < 52; ++m) w[m] = wb[m];

        // exact simplifications of the verified round-1 weights:
        //   w1 = (i+f<=50)?1-f:0  ->  1-f for i<50;  (f==0) for i=50
        //   w2 = (i-1+f>=0)?f:0   ->  0 for i==0;    f for i>=1
        float* wp = data + tid * NA;
        const float w1 = 1.0f - f;
        float prev = ((unsigned)(-k - 1) <= 50u) ? w[0] : 0.0f;
        #pragma unroll
        for (int i = 0; i < NA; ++i) {
            const float cur = ((unsigned)(i - k) <= 50u) ? w[i + 1] : 0.0f;
            float o;
            if (i == 0)           o = w1 * cur + m_lo;
            else if (i == NA - 1) o = ((f == 0.0f) ? cur : f * prev) + m_hi;
            else                  o = w1 * cur + f * prev;
            wp[i] = o;            // own row only; all reads above already issued
            prev = cur;
        }
    }
    // cross-lane writeback -> copy-out visibility (same wave): waitcnt only
    asm volatile("s_waitcnt lgkmcnt(0)" ::: "memory");
    __builtin_amdgcn_sched_barrier(0);

    if (nrows == ROWS) {
        // ---- copy-out: identity b128 LDS reads -> coalesced dwordx4 stores ----
        float4* o4 = (float4*)(out + (size_t)row0 * NA);
        const float4* l4 = (const float4*)data;
        #pragma unroll
        for (int t = 0; t < 12; ++t) o4[t * 64 + tid] = l4[t * 64 + tid];
        if (tid < 48) o4[768 + tid] = l4[768 + tid];
    } else {
        const int nelem = nrows * NA;
        for (int e = tid; e < nelem; e += ROWS)
            out[(size_t)row0 * NA + e] = data[e];
    }
}

extern "C" void kernel_launch(void* const* d_in, const int* in_sizes, int n_in,
                              void* d_out, int out_size, void* d_ws, size_t ws_size,
                              hipStream_t stream) {
    const float* reward = (const float*)d_in[0];
    const float* probs  = (const float*)d_in[1];
    // d_in[2] = atom_values: unused — atom j sits exactly at index j in idx-space
    float* out = (float*)d_out;
    const int bs = in_sizes[0];

    const int blocks = (bs + ROWS - 1) / ROWS;
    c51_bellman_kernel<<<blocks, ROWS, 0, stream>>>(reward, probs, out, bs);
}